// Round 1
// baseline (722.308 us; speedup 1.0000x reference)
//
#include <hip/hip_runtime.h>

// Problem dims (fixed by reference setup_inputs)
#define TT 512
#define BB 8
#define HH 512
#define VV 32000
#define RR (TT * BB)   // 4096 rows (t,b)

__device__ __forceinline__ float clip01(float x) { return fminf(fmaxf(x, 0.0f), 1.0f); }

// --- zero the spike counters (ws is poisoned 0xAA before every timed launch) ---
__global__ void zero_cnt_kernel(int* __restrict__ cnt, int n) {
    int i = blockIdx.x * blockDim.x + threadIdx.x;
    if (i < n) cnt[i] = 0;
}

// --- LIF layer 1: fused embedding gather + positional add + leaky scan.
// 4096 threads, one per (b,h); each scans T sequentially. Spikes are recorded
// as (row -> active h index) lists via atomics (zero cost when no spikes).
__global__ void lif1_kernel(const int* __restrict__ x, const float* __restrict__ emb,
                            const float* __restrict__ pos, const float* __restrict__ beta,
                            int* __restrict__ cnt, int* __restrict__ act) {
    __shared__ int x_lds[TT];
    int tid = blockIdx.x * 256 + threadIdx.x;   // 0..4095
    int b = tid >> 9;
    int h = tid & (HH - 1);
    // this block serves exactly one b (256 consecutive h for fixed b)
    for (int t = threadIdx.x; t < TT; t += 256) x_lds[t] = x[t * BB + b];
    __syncthreads();
    float bt = clip01(beta[h]);
    float m = 0.0f;
    for (int t0 = 0; t0 < TT; t0 += 8) {
        float inp[8];
#pragma unroll
        for (int u = 0; u < 8; ++u) {
            int xv = x_lds[t0 + u];
            inp[u] = emb[xv * HH + h] + pos[(t0 + u) * HH + h];
        }
#pragma unroll
        for (int u = 0; u < 8; ++u) {
            // reset = spike(m_prev - 1) ; m = beta*m_prev + inp - reset ; spk = spike(m - 1)
            float reset = (m > 1.0f) ? 1.0f : 0.0f;  // (m-1>0) == (m>1) exactly in fp32
            m = bt * m + inp[u] - reset;
            if (m > 1.0f) {
                int r = (t0 + u) * BB + b;
                int p = atomicAdd(&cnt[r], 1);
                act[(r << 9) + p] = h;
            }
        }
    }
}

// --- LIF layers 2/3: dense input Z[r][h], same scan, emit active lists. ---
__global__ void lif_scan_kernel(const float* __restrict__ Z, const float* __restrict__ beta,
                                int* __restrict__ cnt, int* __restrict__ act) {
    int tid = blockIdx.x * 256 + threadIdx.x;
    int b = tid >> 9;
    int h = tid & (HH - 1);
    float bt = clip01(beta[h]);
    float m = 0.0f;
    for (int t0 = 0; t0 < TT; t0 += 8) {
        float inp[8];
#pragma unroll
        for (int u = 0; u < 8; ++u) inp[u] = Z[(((t0 + u) * BB + b) << 9) + h];
#pragma unroll
        for (int u = 0; u < 8; ++u) {
            float reset = (m > 1.0f) ? 1.0f : 0.0f;
            m = bt * m + inp[u] - reset;
            if (m > 1.0f) {
                int r = (t0 + u) * BB + b;
                int p = atomicAdd(&cnt[r], 1);
                act[(r << 9) + p] = h;
            }
        }
    }
}

// --- hidden GEMM: Z[r][j] = relu(bias[j] + sum_{k in act[r]} W[j][k]).
// spk entries are exactly 0/1 so summing selected columns is exact. ---
__global__ void sp_gemm_kernel(const int* __restrict__ cnt, const int* __restrict__ act,
                               const float* __restrict__ W, const float* __restrict__ bias,
                               float* __restrict__ Z) {
    int r = blockIdx.x;
    int j = threadIdx.x;            // 512 threads
    int n = cnt[r];                 // broadcast load
    float acc = bias[j];
    const int* a = act + (r << 9);
    for (int i = 0; i < n; ++i) {
        int k = a[i];               // broadcast load
        acc += W[(j << 9) + k];
    }
    Z[(r << 9) + j] = fmaxf(acc, 0.0f);
}

// --- output GEMM: out[r][v] = bout[v] + sum_{k in act[r]} Wout[v][k].
// 8 rows per block to amortize the bout read; float4 stores (write-bound). ---
__global__ void out_gemm_kernel(const int* __restrict__ cnt, const int* __restrict__ act,
                                const float* __restrict__ Wout, const float* __restrict__ bout,
                                float* __restrict__ out) {
    int v = blockIdx.x * 2048 + threadIdx.x * 4;
    if (v >= VV) return;
    float4 bv = *(const float4*)(bout + v);
    int r0 = blockIdx.y * 8;
#pragma unroll
    for (int rr = 0; rr < 8; ++rr) {
        int r = r0 + rr;
        int n = cnt[r];
        float4 acc = bv;
        const int* a = act + (r << 9);
        for (int i = 0; i < n; ++i) {
            int k = a[i];
            acc.x += Wout[(v + 0) * HH + k];
            acc.y += Wout[(v + 1) * HH + k];
            acc.z += Wout[(v + 2) * HH + k];
            acc.w += Wout[(v + 3) * HH + k];
        }
        *(float4*)(out + (size_t)r * VV + v) = acc;
    }
}

extern "C" void kernel_launch(void* const* d_in, const int* in_sizes, int n_in,
                              void* d_out, int out_size, void* d_ws, size_t ws_size,
                              hipStream_t stream) {
    const int*   x     = (const int*)d_in[0];
    const float* emb   = (const float*)d_in[1];
    const float* pos   = (const float*)d_in[2];
    const float* beta1 = (const float*)d_in[3];
    const float* beta2 = (const float*)d_in[4];
    const float* beta3 = (const float*)d_in[5];
    const float* W2    = (const float*)d_in[6];
    const float* b2    = (const float*)d_in[7];
    const float* W3    = (const float*)d_in[8];
    const float* b3    = (const float*)d_in[9];
    const float* Wout  = (const float*)d_in[10];
    const float* bout  = (const float*)d_in[11];
    float* out = (float*)d_out;

    // workspace layout: Z (R*H f32) | actA (R*H i32) | actB (R*H i32) | cntA,cntB,cntC (R i32 each)
    float* Z    = (float*)d_ws;
    int*   actA = (int*)(Z + (size_t)RR * HH);
    int*   actB = actA + (size_t)RR * HH;
    int*   cntA = actB + (size_t)RR * HH;
    int*   cntB = cntA + RR;
    int*   cntC = cntB + RR;

    zero_cnt_kernel<<<(3 * RR + 255) / 256, 256, 0, stream>>>(cntA, 3 * RR);
    lif1_kernel<<<16, 256, 0, stream>>>(x, emb, pos, beta1, cntA, actA);
    sp_gemm_kernel<<<RR, 512, 0, stream>>>(cntA, actA, W2, b2, Z);
    lif_scan_kernel<<<16, 256, 0, stream>>>(Z, beta2, cntB, actB);
    sp_gemm_kernel<<<RR, 512, 0, stream>>>(cntB, actB, W3, b3, Z);
    lif_scan_kernel<<<16, 256, 0, stream>>>(Z, beta3, cntC, actA);  // actA reused for layer 3
    out_gemm_kernel<<<dim3(16, RR / 8), 512, 0, stream>>>(cntC, actA, Wout, bout, out);
}

// Round 2
// 681.866 us; speedup vs baseline: 1.0593x; 1.0593x over previous
//
#include <hip/hip_runtime.h>

// Problem dims (fixed by reference setup_inputs)
#define TT 512
#define BB 8
#define HH 512
#define VV 32000
#define RR (TT * BB)   // 4096 rows (t,b)

__device__ __forceinline__ float clip01(float x) { return fminf(fmaxf(x, 0.0f), 1.0f); }

// --- Stage 0: massively-parallel embedding gather + pos add -> dense hid[r][h].
// Also zeroes the 3*RR spike counters (blocks 0..23). One block per row (t,b).
// This takes the cold-HBM random emb reads out of the latency-bound scan.
__global__ void gather_kernel(const int* __restrict__ x, const float* __restrict__ emb,
                              const float* __restrict__ pos, float* __restrict__ hid,
                              int* __restrict__ cnt_all) {
    int r = blockIdx.x;          // 0..4095, r = t*BB + b
    int h = threadIdx.x;         // 0..511
    int t = r >> 3;
    int xv = x[r];               // broadcast load (x is [T,B] row-major, r == t*B+b)
    hid[((size_t)r << 9) + h] = emb[((size_t)xv << 9) + h] + pos[(t << 9) + h];
    if (r < 3 * RR / HH)         // 24 blocks zero 3*4096 counters
        cnt_all[(r << 9) + h] = 0;
}

// --- LIF layer 1: sequential leaky scan over T, one thread per (b,h).
// Reads L2/L3-hot hid (written by gather). Prefetch depth 16.
__global__ void lif1_kernel(const float* __restrict__ hid, const float* __restrict__ beta,
                            int* __restrict__ cnt, int* __restrict__ act) {
    int b = blockIdx.x;          // 8 blocks
    int h = threadIdx.x;         // 512 threads
    const float* base = hid + ((size_t)b << 9) + h;   // hid[(t*BB+b)*HH + h]
    float bt = clip01(beta[h]);
    float m = 0.0f;
    for (int t0 = 0; t0 < TT; t0 += 16) {
        float inp[16];
#pragma unroll
        for (int u = 0; u < 16; ++u) inp[u] = base[(size_t)(t0 + u) * (BB * HH)];
#pragma unroll
        for (int u = 0; u < 16; ++u) {
            // reset = spike(m_prev - 1); m = beta*m_prev + inp - reset; spk = spike(m - 1)
            float reset = (m > 1.0f) ? 1.0f : 0.0f;   // (m-1>0) == (m>1) exactly in fp32
            m = bt * m + inp[u] - reset;
            if (m > 1.0f) {
                int r = (t0 + u) * BB + b;
                int p = atomicAdd(&cnt[r], 1);
                act[(r << 9) + p] = h;
            }
        }
    }
}

// --- LIF layers 2/3 with the hidden GEMM fused in.
// inp[t][b][h] = relu(bias[h] + sum_{k in act_in[r]} W[h][k])  (spikes are exactly 0/1).
// Per-row spike counts preloaded to LDS; when cnt==0 (common case) the input is a
// per-thread constant -> pure ALU scan, no global traffic.
__global__ void lif_fused_kernel(const int* __restrict__ cnt_in, const int* __restrict__ act_in,
                                 const float* __restrict__ W, const float* __restrict__ bias,
                                 const float* __restrict__ beta,
                                 int* __restrict__ cnt_out, int* __restrict__ act_out) {
    __shared__ int c[TT];
    int b = blockIdx.x;          // 8 blocks
    int h = threadIdx.x;         // 512 threads
    c[h] = cnt_in[h * BB + b];   // h doubles as t-index for the preload
    __syncthreads();
    float bh = bias[h];
    float inp0 = fmaxf(bh, 0.0f);           // relu(bias) when no spikes
    float bt = clip01(beta[h]);
    float m = 0.0f;
    for (int t0 = 0; t0 < TT; t0 += 16) {
        int n[16];
#pragma unroll
        for (int u = 0; u < 16; ++u) n[u] = c[t0 + u];   // batched LDS broadcast reads
#pragma unroll
        for (int u = 0; u < 16; ++u) {
            float inp;
            if (n[u] == 0) {
                inp = inp0;
            } else {                          // rare: sum the spiking columns of W
                float acc = bh;
                const int* a = act_in + (((t0 + u) * BB + b) << 9);
                for (int i = 0; i < n[u]; ++i) acc += W[(h << 9) + a[i]];
                inp = fmaxf(acc, 0.0f);
            }
            float reset = (m > 1.0f) ? 1.0f : 0.0f;
            m = bt * m + inp - reset;
            if (m > 1.0f) {
                int r = (t0 + u) * BB + b;
                int p = atomicAdd(&cnt_out[r], 1);
                act_out[(r << 9) + p] = h;
            }
        }
    }
}

// --- output GEMM: out[r][v] = bout[v] + sum_{k in act[r]} Wout[v][k].
// Write-BW-bound (524 MB); 8 rows/block amortizes the bout read; float4 stores.
__global__ void out_gemm_kernel(const int* __restrict__ cnt, const int* __restrict__ act,
                                const float* __restrict__ Wout, const float* __restrict__ bout,
                                float* __restrict__ out) {
    int v = blockIdx.x * 2048 + threadIdx.x * 4;
    if (v >= VV) return;
    float4 bv = *(const float4*)(bout + v);
    int r0 = blockIdx.y * 8;
#pragma unroll
    for (int rr = 0; rr < 8; ++rr) {
        int r = r0 + rr;
        int n = cnt[r];
        float4 acc = bv;
        const int* a = act + (r << 9);
        for (int i = 0; i < n; ++i) {
            int k = a[i];
            acc.x += Wout[(size_t)(v + 0) * HH + k];
            acc.y += Wout[(size_t)(v + 1) * HH + k];
            acc.z += Wout[(size_t)(v + 2) * HH + k];
            acc.w += Wout[(size_t)(v + 3) * HH + k];
        }
        *(float4*)(out + (size_t)r * VV + v) = acc;
    }
}

extern "C" void kernel_launch(void* const* d_in, const int* in_sizes, int n_in,
                              void* d_out, int out_size, void* d_ws, size_t ws_size,
                              hipStream_t stream) {
    const int*   x     = (const int*)d_in[0];
    const float* emb   = (const float*)d_in[1];
    const float* pos   = (const float*)d_in[2];
    const float* beta1 = (const float*)d_in[3];
    const float* beta2 = (const float*)d_in[4];
    const float* beta3 = (const float*)d_in[5];
    const float* W2    = (const float*)d_in[6];
    const float* b2    = (const float*)d_in[7];
    const float* W3    = (const float*)d_in[8];
    const float* b3    = (const float*)d_in[9];
    const float* Wout  = (const float*)d_in[10];
    const float* bout  = (const float*)d_in[11];
    float* out = (float*)d_out;

    // ws layout: hid (R*H f32) | act1 | act2 | act3 (R*H i32 each) | cnt1,cnt2,cnt3 (R i32 each)
    float* hid  = (float*)d_ws;
    int*   act1 = (int*)(hid + (size_t)RR * HH);
    int*   act2 = act1 + (size_t)RR * HH;
    int*   act3 = act2 + (size_t)RR * HH;
    int*   cnt1 = act3 + (size_t)RR * HH;
    int*   cnt2 = cnt1 + RR;
    int*   cnt3 = cnt2 + RR;

    gather_kernel<<<RR, HH, 0, stream>>>(x, emb, pos, hid, cnt1);
    lif1_kernel<<<BB, HH, 0, stream>>>(hid, beta1, cnt1, act1);
    lif_fused_kernel<<<BB, HH, 0, stream>>>(cnt1, act1, W2, b2, beta2, cnt2, act2);
    lif_fused_kernel<<<BB, HH, 0, stream>>>(cnt2, act2, W3, b3, beta3, cnt3, act3);
    out_gemm_kernel<<<dim3(16, RR / 8), HH, 0, stream>>>(cnt3, act3, Wout, bout, out);
}

// Round 4
// 677.460 us; speedup vs baseline: 1.0662x; 1.0065x over previous
//
#include <hip/hip_runtime.h>

// Problem dims (fixed by reference setup_inputs)
#define TT 512
#define BB 8
#define HH 512
#define VV 32000
#define RR (TT * BB)   // 4096 rows (t,b)

typedef float v4f __attribute__((ext_vector_type(4)));   // native vec for nontemporal store

__device__ __forceinline__ float clip01(float x) { return fminf(fmaxf(x, 0.0f), 1.0f); }

// ---------------------------------------------------------------------------
// Mega-kernel: all three LIF layers fused. 8 blocks (one per batch lane b),
// 512 threads (one per hidden unit h). Key insight: the inter-layer coupling
// (H x H matmul on 0/1 spikes) only needs the PREVIOUS layer's spike list for
// the same b — which this block itself produced. So phases are separated by
// __syncthreads(), spike counts live in LDS, spike index lists go to global
// (read back only on the rare nonzero path).
//
//   phase1: inp = emb[x[t]] + pos[t]          (32-deep prefetch, cold HBM)
//   phase2: inp = relu(b2 + sum_{k in act1} W2[h][k])   (pure ALU when 0 spikes)
//   phase3: inp = relu(b3 + sum_{k in act2} W3[h][k])
// ---------------------------------------------------------------------------
__global__ void __launch_bounds__(512) snn_scan_kernel(
        const int* __restrict__ x, const float* __restrict__ emb,
        const float* __restrict__ pos,
        const float* __restrict__ beta1, const float* __restrict__ beta2,
        const float* __restrict__ beta3,
        const float* __restrict__ W2, const float* __restrict__ b2,
        const float* __restrict__ W3, const float* __restrict__ b3,
        int* __restrict__ act1, int* __restrict__ act2, int* __restrict__ act3,
        int* __restrict__ cnt3_g) {
    __shared__ int x_lds[TT];
    __shared__ int c1[TT], c2[TT], c3[TT];
    const int b = blockIdx.x;    // 0..7
    const int h = threadIdx.x;   // 0..511 (doubles as t-index for preloads)

    x_lds[h] = x[h * BB + b];    // x is [T,B]; t == threadIdx here
    c1[h] = 0; c2[h] = 0; c3[h] = 0;
    __syncthreads();

    // ---- phase 1: embedding-driven LIF ----
    {
        float bt = clip01(beta1[h]);
        float m = 0.0f;
        for (int t0 = 0; t0 < TT; t0 += 32) {
            float ev[32], pv[32];
#pragma unroll
            for (int u = 0; u < 32; ++u) {
                int xv = x_lds[t0 + u];
                ev[u] = emb[((size_t)xv << 9) + h];
                pv[u] = pos[((t0 + u) << 9) + h];
            }
#pragma unroll
            for (int u = 0; u < 32; ++u) {
                float inp = ev[u] + pv[u];
                // reset = spike(m_prev-1); m = beta*m_prev + inp - reset; spk = spike(m-1)
                float reset = (m > 1.0f) ? 1.0f : 0.0f;  // (m-1>0) == (m>1) exactly in fp32
                m = bt * m + inp - reset;
                if (m > 1.0f) {
                    int t = t0 + u;
                    int p = atomicAdd(&c1[t], 1);
                    act1[((t * BB + b) << 9) + p] = h;
                }
            }
        }
    }
    __syncthreads();   // publish c1 (LDS) + act1 (global, same-CU L1) to the block

    // ---- phase 2: hidden layer 2 (fused sparse matmul + LIF) ----
    {
        float bh = b2[h];
        float inp0 = fmaxf(bh, 0.0f);
        float bt = clip01(beta2[h]);
        float m = 0.0f;
        for (int t0 = 0; t0 < TT; t0 += 16) {
            int n[16];
#pragma unroll
            for (int u = 0; u < 16; ++u) n[u] = c1[t0 + u];
#pragma unroll
            for (int u = 0; u < 16; ++u) {
                float inp;
                if (n[u] == 0) {
                    inp = inp0;
                } else {
                    float acc = bh;
                    const int* a = act1 + (((t0 + u) * BB + b) << 9);
                    for (int i = 0; i < n[u]; ++i) acc += W2[(h << 9) + a[i]];
                    inp = fmaxf(acc, 0.0f);
                }
                float reset = (m > 1.0f) ? 1.0f : 0.0f;
                m = bt * m + inp - reset;
                if (m > 1.0f) {
                    int t = t0 + u;
                    int p = atomicAdd(&c2[t], 1);
                    act2[((t * BB + b) << 9) + p] = h;
                }
            }
        }
    }
    __syncthreads();

    // ---- phase 3: hidden layer 3 ----
    {
        float bh = b3[h];
        float inp0 = fmaxf(bh, 0.0f);
        float bt = clip01(beta3[h]);
        float m = 0.0f;
        for (int t0 = 0; t0 < TT; t0 += 16) {
            int n[16];
#pragma unroll
            for (int u = 0; u < 16; ++u) n[u] = c2[t0 + u];
#pragma unroll
            for (int u = 0; u < 16; ++u) {
                float inp;
                if (n[u] == 0) {
                    inp = inp0;
                } else {
                    float acc = bh;
                    const int* a = act2 + (((t0 + u) * BB + b) << 9);
                    for (int i = 0; i < n[u]; ++i) acc += W3[(h << 9) + a[i]];
                    inp = fmaxf(acc, 0.0f);
                }
                float reset = (m > 1.0f) ? 1.0f : 0.0f;
                m = bt * m + inp - reset;
                if (m > 1.0f) {
                    int t = t0 + u;
                    int p = atomicAdd(&c3[t], 1);
                    act3[((t * BB + b) << 9) + p] = h;
                }
            }
        }
    }
    __syncthreads();
    cnt3_g[h * BB + b] = c3[h];   // h doubles as t; export layer-3 counts
}

// ---------------------------------------------------------------------------
// Output GEMM: out[r][v] = bout[v] + sum_{k in act3[r]} Wout[v][k].
// Spikes are exactly 0/1, so summing selected columns is exact. Write-BW
// bound (524 MB): float4 nontemporal streaming stores, 8 rows per block to
// amortize bout/cnt reads.
// ---------------------------------------------------------------------------
__global__ void __launch_bounds__(512) out_gemm_kernel(
        const int* __restrict__ cnt, const int* __restrict__ act,
        const float* __restrict__ Wout, const float* __restrict__ bout,
        float* __restrict__ out) {
    int v = blockIdx.x * 2048 + threadIdx.x * 4;
    if (v >= VV) return;
    float4 bv = *(const float4*)(bout + v);
    int r0 = blockIdx.y * 8;
#pragma unroll
    for (int rr = 0; rr < 8; ++rr) {
        int r = r0 + rr;
        int n = cnt[r];
        float4 acc = bv;
        const int* a = act + (r << 9);
        for (int i = 0; i < n; ++i) {
            int k = a[i];
            acc.x += Wout[(size_t)(v + 0) * HH + k];
            acc.y += Wout[(size_t)(v + 1) * HH + k];
            acc.z += Wout[(size_t)(v + 2) * HH + k];
            acc.w += Wout[(size_t)(v + 3) * HH + k];
        }
        v4f st = {acc.x, acc.y, acc.z, acc.w};
        __builtin_nontemporal_store(st, (v4f*)(out + (size_t)r * VV + v));
    }
}

extern "C" void kernel_launch(void* const* d_in, const int* in_sizes, int n_in,
                              void* d_out, int out_size, void* d_ws, size_t ws_size,
                              hipStream_t stream) {
    const int*   x     = (const int*)d_in[0];
    const float* emb   = (const float*)d_in[1];
    const float* pos   = (const float*)d_in[2];
    const float* beta1 = (const float*)d_in[3];
    const float* beta2 = (const float*)d_in[4];
    const float* beta3 = (const float*)d_in[5];
    const float* W2    = (const float*)d_in[6];
    const float* b2    = (const float*)d_in[7];
    const float* W3    = (const float*)d_in[8];
    const float* b3    = (const float*)d_in[9];
    const float* Wout  = (const float*)d_in[10];
    const float* bout  = (const float*)d_in[11];
    float* out = (float*)d_out;

    // ws layout: act1 | act2 | act3 (R*H i32 each) | cnt3 (R i32)
    int* act1 = (int*)d_ws;
    int* act2 = act1 + (size_t)RR * HH;
    int* act3 = act2 + (size_t)RR * HH;
    int* cnt3 = act3 + (size_t)RR * HH;

    snn_scan_kernel<<<BB, HH, 0, stream>>>(x, emb, pos, beta1, beta2, beta3,
                                           W2, b2, W3, b3, act1, act2, act3, cnt3);
    out_gemm_kernel<<<dim3(16, RR / 8), HH, 0, stream>>>(cnt3, act3, Wout, bout, out);
}